// Round 2
// baseline (979.934 us; speedup 1.0000x reference)
//
#include <hip/hip_runtime.h>
#include <hip/hip_bf16.h>
#include <math.h>

#define T 256
#define N 4000
#define DM 178
#define DI 46
#define H 64
#define DH 64
#define F (DI + DH)   // 110
#define GC 16         // asset chunks per timestep
#define CN (N / GC)   // 250 assets per chunk

// ---------------- Kernel A: xz[t][j] = b_ih[j]+b_hh[j] + x[t,:] . W_ih[j,:] ----------------
__global__ __launch_bounds__(256) void k_xz(const float* __restrict__ x,
    const float* __restrict__ W_ih, const float* __restrict__ b_ih,
    const float* __restrict__ b_hh, float* __restrict__ xz) {
  const int t = blockIdx.x, j = threadIdx.x;   // j in [0,256) == 4H
  __shared__ float xs[DM];
  if (j < DM) xs[j] = x[t * DM + j];
  __syncthreads();
  float acc = b_ih[j] + b_hh[j];
  const float* w = W_ih + j * DM;
  #pragma unroll 2
  for (int k = 0; k < DM; ++k) acc += w[k] * xs[k];
  xz[t * (4 * H) + j] = acc;
}

// ---------------- Kernel B: sequential LSTM scan, one block of 256 threads ----------------
__global__ __launch_bounds__(256) void k_lstm(const float* __restrict__ xz,
    const float* __restrict__ W_hh, float* __restrict__ h_seq) {
  const int j = threadIdx.x;            // gate-preact index [0,256)
  __shared__ float hs[H];
  __shared__ float zs[4 * H];
  // per-thread W_hh row in registers (avoids 64-way LDS bank conflicts)
  float w[H];
  #pragma unroll
  for (int k = 0; k < H; ++k) w[k] = W_hh[j * H + k];
  float c = 0.0f;
  if (j < H) hs[j] = 0.0f;
  __syncthreads();
  for (int t = 0; t < T; ++t) {
    const float zin = xz[t * (4 * H) + j];
    float a0 = 0.f, a1 = 0.f, a2 = 0.f, a3 = 0.f;
    #pragma unroll
    for (int k = 0; k < H; k += 4) {
      a0 += w[k + 0] * hs[k + 0];
      a1 += w[k + 1] * hs[k + 1];
      a2 += w[k + 2] * hs[k + 2];
      a3 += w[k + 3] * hs[k + 3];
    }
    zs[j] = zin + ((a0 + a1) + (a2 + a3));
    __syncthreads();
    if (j < H) {
      const float zi = zs[j], zf = zs[H + j], zg = zs[2 * H + j], zo = zs[3 * H + j];
      const float ig = 1.0f / (1.0f + expf(-zi));
      const float fg = 1.0f / (1.0f + expf(-zf));
      const float gg = tanhf(zg);
      const float og = 1.0f / (1.0f + expf(-zo));
      c = fg * c + ig * gg;
      const float h = og * tanhf(c);
      hs[j] = h;
      h_seq[t * H + j] = h;
    }
    __syncthreads();
  }
}

// ---------------- Kernel C: m1[t][j] = b1[j] + h_seq[t,:] . W1[j, DI:F] ----------------
__global__ __launch_bounds__(64) void k_m1(const float* __restrict__ h_seq,
    const float* __restrict__ W1, const float* __restrict__ b1,
    float* __restrict__ m1g) {
  const int t = blockIdx.x, j = threadIdx.x;   // 64 threads
  __shared__ float hsm[H];
  hsm[j] = h_seq[t * H + j];
  __syncthreads();
  float acc = b1[j];
  const float* w = W1 + j * F + DI;
  #pragma unroll
  for (int k = 0; k < H; ++k) acc += w[k] * hsm[k];
  m1g[t * DH + j] = acc;
}

// ---------------- Kernel D: pointwise MLP + masked partial reduction ----------------
__global__ __launch_bounds__(256) void k_mlp(
    const float* __restrict__ ind, const int* __restrict__ mask,
    const float* __restrict__ ret,
    const float* __restrict__ W1, const float* __restrict__ W2,
    const float* __restrict__ b2, const float* __restrict__ W3,
    const float* __restrict__ b3, const float* __restrict__ m1g,
    float* __restrict__ wout, float* __restrict__ p_wr, float* __restrict__ p_ct) {
  const int t = blockIdx.y;
  const int chunk = blockIdx.x;
  const int tid = threadIdx.x;
  const int n = chunk * CN + tid;
  const bool active = (tid < CN);

  float wr_val = 0.0f, ct_val = 0.0f;
  if (active) {
    const size_t pos = (size_t)t * N + n;
    // load 46 individual features into registers (float2: 8B-aligned since 46*4=184)
    float x[DI];
    const float* ip = ind + pos * DI;
    #pragma unroll
    for (int k = 0; k < DI; k += 2) {
      const float2 v = *reinterpret_cast<const float2*>(ip + k);
      x[k] = v.x; x[k + 1] = v.y;
    }
    // layer 1: a1 = relu(m1[t] + W1[:, :DI] @ x)  -- weights at uniform addrs -> s_load
    float a1[DH];
    #pragma unroll
    for (int j = 0; j < DH; ++j) {
      float acc = m1g[t * DH + j];
      const float* w = W1 + j * F;
      #pragma unroll
      for (int k = 0; k < DI; ++k) acc += w[k] * x[k];
      a1[j] = fmaxf(acc, 0.0f);
    }
    // layers 2+3 fused: wsum = b3 + sum_j W3[j] * relu(b2[j] + W2[j,:] @ a1)
    float wsum = b3[0];
    #pragma unroll
    for (int j = 0; j < DH; ++j) {
      float acc = b2[j];
      const float* w = W2 + j * DH;
      #pragma unroll
      for (int k = 0; k < DH; ++k) acc += w[k] * a1[k];
      wsum += W3[j] * fmaxf(acc, 0.0f);
    }
    const float mf = (mask[pos] != 0) ? 1.0f : 0.0f;
    const float wgt = wsum * mf;
    wout[pos] = wgt;
    wr_val = ret[pos] * wgt;
    ct_val = mf;
  }

  // block reduction: wave butterfly then LDS across the 4 waves
  #pragma unroll
  for (int off = 32; off > 0; off >>= 1) {
    wr_val += __shfl_down(wr_val, off);
    ct_val += __shfl_down(ct_val, off);
  }
  __shared__ float red[8];
  const int wid = tid >> 6, lane = tid & 63;
  if (lane == 0) { red[wid] = wr_val; red[4 + wid] = ct_val; }
  __syncthreads();
  if (tid == 0) {
    const float s = red[0] + red[1] + red[2] + red[3];
    const float c = red[4] + red[5] + red[6] + red[7];
    p_wr[t * GC + chunk] = s;
    p_ct[t * GC + chunk] = c;
  }
}

// ---------------- Kernel E: finalize SDF ----------------
__global__ __launch_bounds__(256) void k_fin(const float* __restrict__ p_wr,
    const float* __restrict__ p_ct, float* __restrict__ out) {
  const int t = threadIdx.x;   // 256 threads == T
  float s = 0.0f, c = 0.0f;
  #pragma unroll
  for (int k = 0; k < GC; ++k) { s += p_wr[t * GC + k]; c += p_ct[t * GC + k]; }
  __shared__ float cs[T];
  cs[t] = c;
  for (int off = 128; off > 0; off >>= 1) {
    __syncthreads();
    if (t < off) cs[t] += cs[t + off];
  }
  __syncthreads();
  const float meanc = cs[0] * (1.0f / (float)T);
  out[t] = s / c * meanc + 1.0f;
}

extern "C" void kernel_launch(void* const* d_in, const int* in_sizes, int n_in,
                              void* d_out, int out_size, void* d_ws, size_t ws_size,
                              hipStream_t stream) {
  const float* macro = (const float*)d_in[0];
  const float* ind   = (const float*)d_in[1];
  const int*   mask  = (const int*)d_in[2];   // jax bool uploaded as int32
  const float* ret   = (const float*)d_in[3];
  const float* W_ih  = (const float*)d_in[4];
  const float* W_hh  = (const float*)d_in[5];
  const float* b_ih  = (const float*)d_in[6];
  const float* b_hh  = (const float*)d_in[7];
  const float* W1    = (const float*)d_in[8];
  const float* b1    = (const float*)d_in[9];
  const float* W2    = (const float*)d_in[10];
  const float* b2    = (const float*)d_in[11];
  const float* W3    = (const float*)d_in[12];
  const float* b3    = (const float*)d_in[13];

  float* out = (float*)d_out;           // [0,256): sdf ; [256, 256+T*N): weights
  float* ws  = (float*)d_ws;
  float* xz    = ws;                    // T*4H   = 65536 floats
  float* h_seq = xz + T * 4 * H;        // T*H    = 16384
  float* m1g   = h_seq + T * H;         // T*DH   = 16384
  float* p_wr  = m1g + T * DH;          // T*GC   = 4096
  float* p_ct  = p_wr + T * GC;         // T*GC   = 4096

  k_xz  <<<dim3(T), dim3(256), 0, stream>>>(macro, W_ih, b_ih, b_hh, xz);
  k_lstm<<<dim3(1), dim3(256), 0, stream>>>(xz, W_hh, h_seq);
  k_m1  <<<dim3(T), dim3(64), 0, stream>>>(h_seq, W1, b1, m1g);
  k_mlp <<<dim3(GC, T), dim3(256), 0, stream>>>(ind, mask, ret, W1, W2, b2, W3, b3,
                                                m1g, out + T, p_wr, p_ct);
  k_fin <<<dim3(1), dim3(T), 0, stream>>>(p_wr, p_ct, out);
}

// Round 3
// 542.336 us; speedup vs baseline: 1.8069x; 1.8069x over previous
//
#include <hip/hip_runtime.h>
#include <hip/hip_bf16.h>
#include <math.h>

#define T 256
#define N 4000
#define DM 178
#define DI 46
#define H 64
#define DH 64
#define F (DI + DH)   // 110
#define GC 16         // asset chunks per timestep
#define CN 250        // assets per chunk

typedef __attribute__((ext_vector_type(8))) short bf16x8;   // 8 bf16 = 4 VGPRs
typedef __attribute__((ext_vector_type(4))) float f32x4;

__device__ inline unsigned int f2bf(float f) {
  __hip_bfloat16 h = __float2bfloat16(f);   // RNE
  unsigned short u;
  __builtin_memcpy(&u, &h, 2);
  return (unsigned int)u;
}

// Swizzled LDS tile helpers: row-major [rows][64 bf16] = 128 B/row,
// byte offset within row XOR'ed by (row&7)<<4 (T2-style, kills the
// 16-lane same-bank pattern on ds_read_b128 A/B-fragment reads).
__device__ inline bf16x8 frag_read(const unsigned int* buf, int row, int kbyte) {
  const int b = (row << 7) + (kbyte ^ ((row & 7) << 4));
  return *reinterpret_cast<const bf16x8*>(reinterpret_cast<const char*>(buf) + b);
}
__device__ inline void sw_write32(unsigned int* buf, int row, int kbyte, unsigned int v) {
  const int b = (row << 7) + (kbyte ^ ((row & 7) << 4));
  buf[b >> 2] = v;
}
__device__ inline void sw_write16(unsigned int* buf, int row, int kbyte, unsigned short v) {
  const int b = (row << 7) + (kbyte ^ ((row & 7) << 4));
  *reinterpret_cast<unsigned short*>(reinterpret_cast<char*>(buf) + b) = v;
}

__device__ inline float frcp(float x) { return __builtin_amdgcn_rcpf(x); }
__device__ inline float fsig(float z) { return frcp(1.f + __expf(-z)); }
__device__ inline float ftanh(float x) {
  const float ax = fabsf(x);
  const float e = __expf(-2.f * ax);
  const float r = (1.f - e) * frcp(1.f + e);
  return copysignf(r, x);
}

// ---------------- Kernel A: xz[t][j] = b_ih[j]+b_hh[j] + x[t,:] . W_ih[j,:] ----------------
__global__ __launch_bounds__(256) void k_xz(const float* __restrict__ x,
    const float* __restrict__ W_ih, const float* __restrict__ b_ih,
    const float* __restrict__ b_hh, float* __restrict__ xz) {
  const int t = blockIdx.x, j = threadIdx.x;
  __shared__ float xs[DM];
  if (j < DM) xs[j] = x[t * DM + j];
  __syncthreads();
  float acc = b_ih[j] + b_hh[j];
  const float* w = W_ih + j * DM;
  #pragma unroll 2
  for (int k = 0; k < DM; ++k) acc += w[k] * xs[k];
  xz[t * (4 * H) + j] = acc;
}

// ---------------- Kernel B: sequential LSTM scan ----------------
// 256 threads (one per gate-preact row). W_hh row in 16 float4 VGPRs,
// hs broadcast via uniform float4 LDS reads, xz[t+1] register-prefetched,
// fast sigmoid/tanh (error ~1e-6).
__global__ __launch_bounds__(256) void k_lstm(const float* __restrict__ xz,
    const float* __restrict__ W_hh, float* __restrict__ h_seq) {
  const int tid = threadIdx.x;
  __shared__ float4 hs4[16];
  __shared__ float zs[256];
  float* hs = reinterpret_cast<float*>(hs4);
  float4 wv4[16];
  const float4* wsrc = reinterpret_cast<const float4*>(W_hh + tid * 64);
  #pragma unroll
  for (int k = 0; k < 16; ++k) wv4[k] = wsrc[k];
  float c = 0.f;
  if (tid < H) hs[tid] = 0.f;
  float znext = xz[tid];   // t = 0
  __syncthreads();
  for (int t = 0; t < T; ++t) {
    const float zcur = znext;
    if (t + 1 < T) znext = xz[(t + 1) * 256 + tid];   // hide global latency under dot
    float a0 = 0.f, a1 = 0.f, a2 = 0.f, a3 = 0.f;
    #pragma unroll
    for (int k = 0; k < 16; ++k) {
      const float4 hv = hs4[k];   // uniform address -> LDS broadcast
      a0 += wv4[k].x * hv.x; a1 += wv4[k].y * hv.y;
      a2 += wv4[k].z * hv.z; a3 += wv4[k].w * hv.w;
    }
    zs[tid] = zcur + ((a0 + a1) + (a2 + a3));
    __syncthreads();
    if (tid < H) {
      const float zi = zs[tid], zf = zs[H + tid], zg = zs[2 * H + tid], zo = zs[3 * H + tid];
      const float ig = fsig(zi), fg = fsig(zf), og = fsig(zo);
      const float gg = ftanh(zg);
      c = fg * c + ig * gg;
      const float h = og * ftanh(c);
      hs[tid] = h;
      h_seq[t * H + tid] = h;
    }
    __syncthreads();
  }
}

// ---------------- Kernel C: m1[t][j] = b1[j] + h_seq[t,:] . W1[j, DI:F] ----------------
__global__ __launch_bounds__(64) void k_m1(const float* __restrict__ h_seq,
    const float* __restrict__ W1, const float* __restrict__ b1,
    float* __restrict__ m1g) {
  const int t = blockIdx.x, j = threadIdx.x;
  __shared__ float hsm[H];
  hsm[j] = h_seq[t * H + j];
  __syncthreads();
  float acc = b1[j];
  const float* w = W1 + j * F + DI;
  #pragma unroll
  for (int k = 0; k < H; ++k) acc += w[k] * hsm[k];
  m1g[t * DH + j] = acc;
}

// ---------------- Kernel D: MFMA pointwise MLP + masked partial reduction ----------------
// Block = (t, chunk of 250 assets), 256 threads / 4 waves. Each wave owns 64
// asset rows (4 M-tiles of 16). Layer1: C1[M][64] = Xbf16[M][64] x W1ind^T,
// +m1g, relu -> bf16 back into the X LDS buffer (per-wave in-order DS, no
// barrier needed). Layer2 likewise; layer3 + mask + reduce in epilogue.
__global__ __launch_bounds__(256) void k_mlp(
    const float* __restrict__ ind, const int* __restrict__ mask,
    const float* __restrict__ ret,
    const float* __restrict__ W1, const float* __restrict__ W2,
    const float* __restrict__ b2, const float* __restrict__ W3,
    const float* __restrict__ b3, const float* __restrict__ m1g,
    float* __restrict__ wout, float* __restrict__ p_wr, float* __restrict__ p_ct) {
  const int t = blockIdx.y, chunk = blockIdx.x, tid = threadIdx.x;
  const int lr = tid & 15;          // row/col within 16-tile
  const int lq = (tid >> 4) & 3;    // k-quad / row-quad
  const int wv = tid >> 6;          // wave id

  __shared__ unsigned int XB[8192];   // 32 KB: X bf16 [256][64] swz; reused for A1
  __shared__ unsigned int WB1[2048];  // 8 KB: W1ind [64 n][64 k] swz (k>=46 zero)
  __shared__ unsigned int WB2[2048];  // 8 KB: W2    [64 n][64 k] swz
  __shared__ float m1s[DH], b2s[DH], w3s[DH];
  __shared__ float ws_sum[256];
  __shared__ float red[8];

  // zero X (covers row 250..255 and k-padding) and W1 k-padding
  #pragma unroll
  for (int i = 0; i < 32; ++i) XB[tid + 256 * i] = 0u;
  #pragma unroll
  for (int i = 0; i < 8; ++i) WB1[tid + 256 * i] = 0u;
  __syncthreads();

  const size_t pos0 = (size_t)t * N + (size_t)chunk * CN;
  // stage X: 250 rows x 46 fp32 (fully coalesced float2) -> bf16 pairs
  const float* xbase = ind + pos0 * DI;
  for (int i = tid; i < CN * DI / 2; i += 256) {   // 5750 pairs, 46 = 2*23
    const float2 v = *reinterpret_cast<const float2*>(xbase + 2 * i);
    const int row = i / 23, kp = i - row * 23;
    sw_write32(XB, row, kp * 4, f2bf(v.x) | (f2bf(v.y) << 16));
  }
  // stage W1ind: B1[k][n] = W1[n][k] -> store rows n = W1 rows (first 46 cols)
  for (int i = tid; i < 64 * 23; i += 256) {
    const int n = i / 23, kp = i - n * 23;
    const float2 v = *reinterpret_cast<const float2*>(W1 + n * F + 2 * kp);
    sw_write32(WB1, n, kp * 4, f2bf(v.x) | (f2bf(v.y) << 16));
  }
  // stage W2 (row-major already matches B2[k][j] = W2[j][k])
  for (int i = tid; i < 64 * 32; i += 256) {
    const int n = i >> 5, kp = i & 31;
    const float2 v = *reinterpret_cast<const float2*>(W2 + n * DH + 2 * kp);
    sw_write32(WB2, n, kp * 4, f2bf(v.x) | (f2bf(v.y) << 16));
  }
  if (tid < DH) { m1s[tid] = m1g[t * DH + tid]; b2s[tid] = b2[tid]; w3s[tid] = W3[tid]; }
  __syncthreads();

  // ---- layer 1 ----
  bf16x8 b1f[4][2];
  #pragma unroll
  for (int nt = 0; nt < 4; ++nt)
    #pragma unroll
    for (int ks = 0; ks < 2; ++ks)
      b1f[nt][ks] = frag_read(WB1, nt * 16 + lr, ks * 64 + lq * 16);

  const int rbase = wv * 64;
  #pragma unroll
  for (int mt = 0; mt < 4; ++mt) {
    const int arow = rbase + mt * 16 + lr;
    const bf16x8 a0 = frag_read(XB, arow, lq * 16);
    const bf16x8 a1 = frag_read(XB, arow, 64 + lq * 16);
    #pragma unroll
    for (int nt = 0; nt < 4; ++nt) {
      f32x4 acc = {0.f, 0.f, 0.f, 0.f};
      acc = __builtin_amdgcn_mfma_f32_16x16x32_bf16(a0, b1f[nt][0], acc, 0, 0, 0);
      acc = __builtin_amdgcn_mfma_f32_16x16x32_bf16(a1, b1f[nt][1], acc, 0, 0, 0);
      const int col = nt * 16 + lr;                    // C: col = lane&15
      const float mv = m1s[col];
      #pragma unroll
      for (int r = 0; r < 4; ++r) {                    // C: row = (lane>>4)*4 + r
        const float v = fmaxf(acc[r] + mv, 0.f);
        sw_write16(XB, rbase + mt * 16 + lq * 4 + r, col * 2, (unsigned short)f2bf(v));
      }
    }
  }

  // ---- layer 2 + 3 ----
  bf16x8 b2f[4][2];
  #pragma unroll
  for (int nt = 0; nt < 4; ++nt)
    #pragma unroll
    for (int ks = 0; ks < 2; ++ks)
      b2f[nt][ks] = frag_read(WB2, nt * 16 + lr, ks * 64 + lq * 16);
  const float b3v = b3[0];

  #pragma unroll
  for (int mt = 0; mt < 4; ++mt) {
    const int arow = rbase + mt * 16 + lr;
    const bf16x8 a0 = frag_read(XB, arow, lq * 16);
    const bf16x8 a1 = frag_read(XB, arow, 64 + lq * 16);
    float s0 = 0.f, s1 = 0.f, s2 = 0.f, s3 = 0.f;
    #pragma unroll
    for (int nt = 0; nt < 4; ++nt) {
      f32x4 acc = {0.f, 0.f, 0.f, 0.f};
      acc = __builtin_amdgcn_mfma_f32_16x16x32_bf16(a0, b2f[nt][0], acc, 0, 0, 0);
      acc = __builtin_amdgcn_mfma_f32_16x16x32_bf16(a1, b2f[nt][1], acc, 0, 0, 0);
      const int col = nt * 16 + lr;
      const float bb = b2s[col], w3 = w3s[col];
      s0 += w3 * fmaxf(acc[0] + bb, 0.f);
      s1 += w3 * fmaxf(acc[1] + bb, 0.f);
      s2 += w3 * fmaxf(acc[2] + bb, 0.f);
      s3 += w3 * fmaxf(acc[3] + bb, 0.f);
    }
    // reduce over the 16-lane col dimension
    #pragma unroll
    for (int off = 1; off < 16; off <<= 1) {
      s0 += __shfl_xor(s0, off);
      s1 += __shfl_xor(s1, off);
      s2 += __shfl_xor(s2, off);
      s3 += __shfl_xor(s3, off);
    }
    if (lr < 4) {
      const float v = (lr == 0) ? s0 : (lr == 1) ? s1 : (lr == 2) ? s2 : s3;
      ws_sum[rbase + mt * 16 + lq * 4 + lr] = v + b3v;
    }
  }
  __syncthreads();

  // ---- tail: mask, store weights, partial reduction (coalesced) ----
  float wr_val = 0.f, ct_val = 0.f;
  if (tid < CN) {
    const size_t pos = pos0 + tid;
    const float mf = (mask[pos] != 0) ? 1.f : 0.f;
    const float wgt = ws_sum[tid] * mf;
    wout[pos] = wgt;
    wr_val = ret[pos] * wgt;
    ct_val = mf;
  }
  #pragma unroll
  for (int off = 32; off > 0; off >>= 1) {
    wr_val += __shfl_down(wr_val, off);
    ct_val += __shfl_down(ct_val, off);
  }
  if ((tid & 63) == 0) { red[wv] = wr_val; red[4 + wv] = ct_val; }
  __syncthreads();
  if (tid == 0) {
    p_wr[t * GC + chunk] = red[0] + red[1] + red[2] + red[3];
    p_ct[t * GC + chunk] = red[4] + red[5] + red[6] + red[7];
  }
}

// ---------------- Kernel E: finalize SDF ----------------
__global__ __launch_bounds__(256) void k_fin(const float* __restrict__ p_wr,
    const float* __restrict__ p_ct, float* __restrict__ out) {
  const int t = threadIdx.x;
  float s = 0.f, c = 0.f;
  #pragma unroll
  for (int k = 0; k < GC; ++k) { s += p_wr[t * GC + k]; c += p_ct[t * GC + k]; }
  __shared__ float cs[T];
  cs[t] = c;
  for (int off = 128; off > 0; off >>= 1) {
    __syncthreads();
    if (t < off) cs[t] += cs[t + off];
  }
  __syncthreads();
  const float meanc = cs[0] * (1.0f / (float)T);
  out[t] = s / c * meanc + 1.0f;
}

extern "C" void kernel_launch(void* const* d_in, const int* in_sizes, int n_in,
                              void* d_out, int out_size, void* d_ws, size_t ws_size,
                              hipStream_t stream) {
  const float* macro = (const float*)d_in[0];
  const float* ind   = (const float*)d_in[1];
  const int*   mask  = (const int*)d_in[2];   // jax bool uploaded as int32
  const float* ret   = (const float*)d_in[3];
  const float* W_ih  = (const float*)d_in[4];
  const float* W_hh  = (const float*)d_in[5];
  const float* b_ih  = (const float*)d_in[6];
  const float* b_hh  = (const float*)d_in[7];
  const float* W1    = (const float*)d_in[8];
  const float* b1    = (const float*)d_in[9];
  const float* W2    = (const float*)d_in[10];
  const float* b2    = (const float*)d_in[11];
  const float* W3    = (const float*)d_in[12];
  const float* b3    = (const float*)d_in[13];

  float* out = (float*)d_out;           // [0,256): sdf ; [256, 256+T*N): weights
  float* ws  = (float*)d_ws;
  float* xz    = ws;                    // T*4H   = 65536 floats
  float* h_seq = xz + T * 4 * H;        // T*H    = 16384
  float* m1g   = h_seq + T * H;         // T*DH   = 16384
  float* p_wr  = m1g + T * DH;          // T*GC   = 4096
  float* p_ct  = p_wr + T * GC;         // T*GC   = 4096

  k_xz  <<<dim3(T), dim3(256), 0, stream>>>(macro, W_ih, b_ih, b_hh, xz);
  k_lstm<<<dim3(1), dim3(256), 0, stream>>>(xz, W_hh, h_seq);
  k_m1  <<<dim3(T), dim3(64), 0, stream>>>(h_seq, W1, b1, m1g);
  k_mlp <<<dim3(GC, T), dim3(256), 0, stream>>>(ind, mask, ret, W1, W2, b2, W3, b3,
                                                m1g, out + T, p_wr, p_ct);
  k_fin <<<dim3(1), dim3(T), 0, stream>>>(p_wr, p_ct, out);
}

// Round 4
// 528.721 us; speedup vs baseline: 1.8534x; 1.0258x over previous
//
#include <hip/hip_runtime.h>
#include <hip/hip_bf16.h>
#include <math.h>

#define T 256
#define N 4000
#define DM 178
#define DI 46
#define H 64
#define DH 64
#define F (DI + DH)   // 110
#define GC 16         // asset chunks per timestep
#define CN 250        // assets per chunk

typedef __attribute__((ext_vector_type(8))) short bf16x8;   // 8 bf16 = 4 VGPRs
typedef __attribute__((ext_vector_type(4))) float f32x4;

__device__ inline unsigned int f2bf(float f) {
  __hip_bfloat16 h = __float2bfloat16(f);   // RNE
  unsigned short u;
  __builtin_memcpy(&u, &h, 2);
  return (unsigned int)u;
}

// Swizzled LDS tile helpers: row-major [rows][64 bf16] = 128 B/row,
// byte offset within row XOR'ed by (row&7)<<4 (T2-style, kills the
// 16-lane same-bank pattern on ds_read_b128 A/B-fragment reads).
__device__ inline bf16x8 frag_read(const unsigned int* buf, int row, int kbyte) {
  const int b = (row << 7) + (kbyte ^ ((row & 7) << 4));
  return *reinterpret_cast<const bf16x8*>(reinterpret_cast<const char*>(buf) + b);
}
__device__ inline void sw_write32(unsigned int* buf, int row, int kbyte, unsigned int v) {
  const int b = (row << 7) + (kbyte ^ ((row & 7) << 4));
  buf[b >> 2] = v;
}
__device__ inline void sw_write16(unsigned int* buf, int row, int kbyte, unsigned short v) {
  const int b = (row << 7) + (kbyte ^ ((row & 7) << 4));
  *reinterpret_cast<unsigned short*>(reinterpret_cast<char*>(buf) + b) = v;
}

__device__ inline float frcp(float x) { return __builtin_amdgcn_rcpf(x); }
__device__ inline float fsig(float z) { return frcp(1.f + __expf(-z)); }
__device__ inline float ftanh(float x) {
  const float ax = fabsf(x);
  const float e = __expf(-2.f * ax);
  const float r = (1.f - e) * frcp(1.f + e);
  return copysignf(r, x);
}

// ---------------- Kernel A: xz[t][j] = b_ih[j]+b_hh[j] + x[t,:] . W_ih[j,:] ----------------
__global__ __launch_bounds__(256) void k_xz(const float* __restrict__ x,
    const float* __restrict__ W_ih, const float* __restrict__ b_ih,
    const float* __restrict__ b_hh, float* __restrict__ xz) {
  const int t = blockIdx.x, j = threadIdx.x;
  __shared__ float xs[DM];
  if (j < DM) xs[j] = x[t * DM + j];
  __syncthreads();
  float acc = b_ih[j] + b_hh[j];
  const float* w = W_ih + j * DM;
  #pragma unroll 2
  for (int k = 0; k < DM; ++k) acc += w[k] * xs[k];
  xz[t * (4 * H) + j] = acc;
}

// ---------------- Kernel B: sequential LSTM scan, 1 barrier/step ----------------
// 4 waves; wave w owns gate block w (rows w*64..w*64+63 of the preactivation).
// Every wave redundantly maintains the full (h,c) state: lane j holds c_j, and
// each wave keeps a PRIVATE LDS copy of h (hsw[w]) so the next step's dot has
// no cross-wave dependency. Gate activations are computed in parallel by all
// 4 waves (wave-uniform tanh/sigmoid split) and exchanged through a
// double-buffered acts[] with a single __syncthreads per step.
__global__ __launch_bounds__(256) void k_lstm(const float* __restrict__ xz,
    const float* __restrict__ W_hh, float* __restrict__ h_seq) {
  const int tid = threadIdx.x;
  const int wv = tid >> 6;      // wave = gate (0:i 1:f 2:g 3:o, torch order)
  const int j  = tid & 63;      // hidden index
  __shared__ float4 hsw[4][16];     // per-wave private h copy
  __shared__ float acts[2][256];    // double-buffered gate activations

  float4 wv4[16];   // W_hh row `tid` (gate-preact row) in registers
  const float4* wsrc = reinterpret_cast<const float4*>(W_hh + tid * H);
  #pragma unroll
  for (int k = 0; k < 16; ++k) wv4[k] = wsrc[k];

  float c = 0.f;
  if (j < 16) hsw[wv][j] = make_float4(0.f, 0.f, 0.f, 0.f);
  float znext = xz[tid];   // t = 0
  __syncthreads();

  for (int t = 0; t < T; ++t) {
    const float zcur = znext;
    if (t + 1 < T) znext = xz[(t + 1) * 256 + tid];   // hide global latency
    // dot over own-wave h copy (uniform float4 broadcast reads)
    float a0 = 0.f, a1 = 0.f, a2 = 0.f, a3 = 0.f;
    #pragma unroll
    for (int k = 0; k < 16; ++k) {
      const float4 hv = hsw[wv][k];
      a0 += wv4[k].x * hv.x; a1 += wv4[k].y * hv.y;
      a2 += wv4[k].z * hv.z; a3 += wv4[k].w * hv.w;
    }
    const float z = zcur + ((a0 + a1) + (a2 + a3));
    // activation in parallel across waves; branch is wave-uniform
    const float act = (wv == 2) ? ftanh(z) : fsig(z);
    acts[t & 1][tid] = act;
    __syncthreads();   // the ONLY barrier per step
    const float gi = acts[t & 1][j];
    const float gf = acts[t & 1][H + j];
    const float gg = acts[t & 1][2 * H + j];
    const float go = acts[t & 1][3 * H + j];
    c = gf * c + gi * gg;                  // redundant in all 4 waves (identical)
    const float h = go * ftanh(c);
    reinterpret_cast<float*>(&hsw[wv][0])[j] = h;   // wave-private: no barrier
    if (wv == 0) h_seq[t * H + j] = h;
  }
}

// ---------------- Kernel C: m1[t][j] = b1[j] + h_seq[t,:] . W1[j, DI:F] ----------------
__global__ __launch_bounds__(64) void k_m1(const float* __restrict__ h_seq,
    const float* __restrict__ W1, const float* __restrict__ b1,
    float* __restrict__ m1g) {
  const int t = blockIdx.x, j = threadIdx.x;
  __shared__ float hsm[H];
  hsm[j] = h_seq[t * H + j];
  __syncthreads();
  float acc = b1[j];
  const float* w = W1 + j * F + DI;
  #pragma unroll
  for (int k = 0; k < H; ++k) acc += w[k] * hsm[k];
  m1g[t * DH + j] = acc;
}

// ---------------- Kernel D: MFMA pointwise MLP + masked partial reduction ----------------
__global__ __launch_bounds__(256) void k_mlp(
    const float* __restrict__ ind, const int* __restrict__ mask,
    const float* __restrict__ ret,
    const float* __restrict__ W1, const float* __restrict__ W2,
    const float* __restrict__ b2, const float* __restrict__ W3,
    const float* __restrict__ b3, const float* __restrict__ m1g,
    float* __restrict__ wout, float* __restrict__ p_wr, float* __restrict__ p_ct) {
  const int t = blockIdx.y, chunk = blockIdx.x, tid = threadIdx.x;
  const int lr = tid & 15;          // row/col within 16-tile
  const int lq = (tid >> 4) & 3;    // k-quad / row-quad
  const int wv = tid >> 6;          // wave id

  __shared__ unsigned int XB[8192];   // 32 KB: X bf16 [256][64] swz; reused for A1
  __shared__ unsigned int WB1[2048];  // 8 KB: W1ind [64 n][64 k] swz (k>=46 zero)
  __shared__ unsigned int WB2[2048];  // 8 KB: W2    [64 n][64 k] swz
  __shared__ float m1s[DH], b2s[DH], w3s[DH];
  __shared__ float ws_sum[256];
  __shared__ float red[8];

  // zero X (covers row 250..255 and k-padding) and W1 k-padding
  #pragma unroll
  for (int i = 0; i < 32; ++i) XB[tid + 256 * i] = 0u;
  #pragma unroll
  for (int i = 0; i < 8; ++i) WB1[tid + 256 * i] = 0u;
  __syncthreads();

  const size_t pos0 = (size_t)t * N + (size_t)chunk * CN;
  // stage X: 250 rows x 46 fp32 (fully coalesced float2) -> bf16 pairs
  const float* xbase = ind + pos0 * DI;
  for (int i = tid; i < CN * DI / 2; i += 256) {   // 5750 pairs, 46 = 2*23
    const float2 v = *reinterpret_cast<const float2*>(xbase + 2 * i);
    const int row = i / 23, kp = i - row * 23;
    sw_write32(XB, row, kp * 4, f2bf(v.x) | (f2bf(v.y) << 16));
  }
  // stage W1ind: rows n = W1 rows (first 46 cols)
  for (int i = tid; i < 64 * 23; i += 256) {
    const int n = i / 23, kp = i - n * 23;
    const float2 v = *reinterpret_cast<const float2*>(W1 + n * F + 2 * kp);
    sw_write32(WB1, n, kp * 4, f2bf(v.x) | (f2bf(v.y) << 16));
  }
  // stage W2 (row-major already matches B2[k][j] = W2[j][k])
  for (int i = tid; i < 64 * 32; i += 256) {
    const int n = i >> 5, kp = i & 31;
    const float2 v = *reinterpret_cast<const float2*>(W2 + n * DH + 2 * kp);
    sw_write32(WB2, n, kp * 4, f2bf(v.x) | (f2bf(v.y) << 16));
  }
  if (tid < DH) { m1s[tid] = m1g[t * DH + tid]; b2s[tid] = b2[tid]; w3s[tid] = W3[tid]; }
  __syncthreads();

  // ---- layer 1 ----
  bf16x8 b1f[4][2];
  #pragma unroll
  for (int nt = 0; nt < 4; ++nt)
    #pragma unroll
    for (int ks = 0; ks < 2; ++ks)
      b1f[nt][ks] = frag_read(WB1, nt * 16 + lr, ks * 64 + lq * 16);

  const int rbase = wv * 64;
  #pragma unroll
  for (int mt = 0; mt < 4; ++mt) {
    const int arow = rbase + mt * 16 + lr;
    const bf16x8 a0 = frag_read(XB, arow, lq * 16);
    const bf16x8 a1 = frag_read(XB, arow, 64 + lq * 16);
    #pragma unroll
    for (int nt = 0; nt < 4; ++nt) {
      f32x4 acc = {0.f, 0.f, 0.f, 0.f};
      acc = __builtin_amdgcn_mfma_f32_16x16x32_bf16(a0, b1f[nt][0], acc, 0, 0, 0);
      acc = __builtin_amdgcn_mfma_f32_16x16x32_bf16(a1, b1f[nt][1], acc, 0, 0, 0);
      const int col = nt * 16 + lr;                    // C: col = lane&15
      const float mv = m1s[col];
      #pragma unroll
      for (int r = 0; r < 4; ++r) {                    // C: row = (lane>>4)*4 + r
        const float v = fmaxf(acc[r] + mv, 0.f);
        sw_write16(XB, rbase + mt * 16 + lq * 4 + r, col * 2, (unsigned short)f2bf(v));
      }
    }
  }

  // ---- layer 2 + 3 ----
  bf16x8 b2f[4][2];
  #pragma unroll
  for (int nt = 0; nt < 4; ++nt)
    #pragma unroll
    for (int ks = 0; ks < 2; ++ks)
      b2f[nt][ks] = frag_read(WB2, nt * 16 + lr, ks * 64 + lq * 16);
  const float b3v = b3[0];

  #pragma unroll
  for (int mt = 0; mt < 4; ++mt) {
    const int arow = rbase + mt * 16 + lr;
    const bf16x8 a0 = frag_read(XB, arow, lq * 16);
    const bf16x8 a1 = frag_read(XB, arow, 64 + lq * 16);
    float s0 = 0.f, s1 = 0.f, s2 = 0.f, s3 = 0.f;
    #pragma unroll
    for (int nt = 0; nt < 4; ++nt) {
      f32x4 acc = {0.f, 0.f, 0.f, 0.f};
      acc = __builtin_amdgcn_mfma_f32_16x16x32_bf16(a0, b2f[nt][0], acc, 0, 0, 0);
      acc = __builtin_amdgcn_mfma_f32_16x16x32_bf16(a1, b2f[nt][1], acc, 0, 0, 0);
      const int col = nt * 16 + lr;
      const float bb = b2s[col], w3 = w3s[col];
      s0 += w3 * fmaxf(acc[0] + bb, 0.f);
      s1 += w3 * fmaxf(acc[1] + bb, 0.f);
      s2 += w3 * fmaxf(acc[2] + bb, 0.f);
      s3 += w3 * fmaxf(acc[3] + bb, 0.f);
    }
    #pragma unroll
    for (int off = 1; off < 16; off <<= 1) {
      s0 += __shfl_xor(s0, off);
      s1 += __shfl_xor(s1, off);
      s2 += __shfl_xor(s2, off);
      s3 += __shfl_xor(s3, off);
    }
    if (lr < 4) {
      const float v = (lr == 0) ? s0 : (lr == 1) ? s1 : (lr == 2) ? s2 : s3;
      ws_sum[rbase + mt * 16 + lq * 4 + lr] = v + b3v;
    }
  }
  __syncthreads();

  // ---- tail: mask, store weights, partial reduction (coalesced) ----
  float wr_val = 0.f, ct_val = 0.f;
  if (tid < CN) {
    const size_t pos = pos0 + tid;
    const float mf = (mask[pos] != 0) ? 1.f : 0.f;
    const float wgt = ws_sum[tid] * mf;
    wout[pos] = wgt;
    wr_val = ret[pos] * wgt;
    ct_val = mf;
  }
  #pragma unroll
  for (int off = 32; off > 0; off >>= 1) {
    wr_val += __shfl_down(wr_val, off);
    ct_val += __shfl_down(ct_val, off);
  }
  if ((tid & 63) == 0) { red[wv] = wr_val; red[4 + wv] = ct_val; }
  __syncthreads();
  if (tid == 0) {
    p_wr[t * GC + chunk] = red[0] + red[1] + red[2] + red[3];
    p_ct[t * GC + chunk] = red[4] + red[5] + red[6] + red[7];
  }
}

// ---------------- Kernel E: finalize SDF ----------------
__global__ __launch_bounds__(256) void k_fin(const float* __restrict__ p_wr,
    const float* __restrict__ p_ct, float* __restrict__ out) {
  const int t = threadIdx.x;
  float s = 0.f, c = 0.f;
  #pragma unroll
  for (int k = 0; k < GC; ++k) { s += p_wr[t * GC + k]; c += p_ct[t * GC + k]; }
  __shared__ float cs[T];
  cs[t] = c;
  for (int off = 128; off > 0; off >>= 1) {
    __syncthreads();
    if (t < off) cs[t] += cs[t + off];
  }
  __syncthreads();
  const float meanc = cs[0] * (1.0f / (float)T);
  out[t] = s / c * meanc + 1.0f;
}

extern "C" void kernel_launch(void* const* d_in, const int* in_sizes, int n_in,
                              void* d_out, int out_size, void* d_ws, size_t ws_size,
                              hipStream_t stream) {
  const float* macro = (const float*)d_in[0];
  const float* ind   = (const float*)d_in[1];
  const int*   mask  = (const int*)d_in[2];   // jax bool uploaded as int32
  const float* ret   = (const float*)d_in[3];
  const float* W_ih  = (const float*)d_in[4];
  const float* W_hh  = (const float*)d_in[5];
  const float* b_ih  = (const float*)d_in[6];
  const float* b_hh  = (const float*)d_in[7];
  const float* W1    = (const float*)d_in[8];
  const float* b1    = (const float*)d_in[9];
  const float* W2    = (const float*)d_in[10];
  const float* b2    = (const float*)d_in[11];
  const float* W3    = (const float*)d_in[12];
  const float* b3    = (const float*)d_in[13];

  float* out = (float*)d_out;           // [0,256): sdf ; [256, 256+T*N): weights
  float* ws  = (float*)d_ws;
  float* xz    = ws;                    // T*4H   = 65536 floats
  float* h_seq = xz + T * 4 * H;        // T*H    = 16384
  float* m1g   = h_seq + T * H;         // T*DH   = 16384
  float* p_wr  = m1g + T * DH;          // T*GC   = 4096
  float* p_ct  = p_wr + T * GC;         // T*GC   = 4096

  k_xz  <<<dim3(T), dim3(256), 0, stream>>>(macro, W_ih, b_ih, b_hh, xz);
  k_lstm<<<dim3(1), dim3(256), 0, stream>>>(xz, W_hh, h_seq);
  k_m1  <<<dim3(T), dim3(64), 0, stream>>>(h_seq, W1, b1, m1g);
  k_mlp <<<dim3(GC, T), dim3(256), 0, stream>>>(ind, mask, ret, W1, W2, b2, W3, b3,
                                                m1g, out + T, p_wr, p_ct);
  k_fin <<<dim3(1), dim3(T), 0, stream>>>(p_wr, p_ct, out);
}